// Round 9
// baseline (697.190 us; speedup 1.0000x reference)
//
#include <hip/hip_runtime.h>
#include <hip/hip_bf16.h>

#define TTLEN 2048
#define NCH   64
#define CLEN  32    // TTLEN / NCH
#define NBLK  512   // persistent grid; 2 blocks/CU by LDS (64KiB)

typedef unsigned short ushort_t;
typedef __attribute__((ext_vector_type(8))) short short8;
typedef __attribute__((ext_vector_type(4))) float f32x4;

__device__ __forceinline__ unsigned short f2bf(float f) {
    __hip_bfloat16 h = __float2bfloat16(f);
    return *reinterpret_cast<unsigned short*>(&h);
}
__device__ __forceinline__ float bf2f(unsigned int u16) {
    union { unsigned int i; float f; } v; v.i = u16 << 16; return v.f;
}

#define GLD_LDS16(gp, lp) __builtin_amdgcn_global_load_lds( \
    (const __attribute__((address_space(1))) void*)(gp),    \
    (__attribute__((address_space(3))) void*)(lp), 16, 0, 0)

// ---- software grid barrier: arrival = 1 RMW/block; POLL = coherent LOAD (no RMW!) ----
// r8's atomicAdd(p,0) poll serialized 511 RMWs at the LLC (~85us/barrier). Acquire
// loads at agent scope take the coherent LLC path without serializing.
// bar[0] = arrive count, bar[1] = generation; zeroed by hipMemsetAsync pre-launch.
__device__ __forceinline__ void gbar(unsigned int* bar) {
    __threadfence();                       // release: my writes visible device-wide
    __syncthreads();                       // whole block arrived
    if (threadIdx.x == 0) {
        unsigned int g = __hip_atomic_load(&bar[1], __ATOMIC_RELAXED,
                                           __HIP_MEMORY_SCOPE_AGENT);
        unsigned int a = __hip_atomic_fetch_add(&bar[0], 1u, __ATOMIC_ACQ_REL,
                                                __HIP_MEMORY_SCOPE_AGENT);
        if (a == NBLK - 1u) {
            __hip_atomic_store(&bar[0], 0u, __ATOMIC_RELAXED,
                               __HIP_MEMORY_SCOPE_AGENT);   // none reads cnt till flip
            __hip_atomic_fetch_add(&bar[1], 1u, __ATOMIC_RELEASE,
                                   __HIP_MEMORY_SCOPE_AGENT);
        } else {
            while (__hip_atomic_load(&bar[1], __ATOMIC_ACQUIRE,
                                     __HIP_MEMORY_SCOPE_AGENT) == g)
                __builtin_amdgcn_s_sleep(8);               // ~0.2us poll interval
        }
        __threadfence();                   // acquire: invalidate stale cache lines
    }
    __syncthreads();
}

// ================== single persistent kernel, 5 phases ==================
// Phase 2/5 GEMM = r6-verified: 2-buffer LDS ping-pong, counted vmcnt(8),
// raw s_barrier, LDS-repack dwordx4 epilogue, M-fast job order.
// Scans = r0/r5-verified shapes. Phase bodies byte-identical to r8 (which passed).
__global__ void __launch_bounds__(256, 2)
rwkv_fused(const float* __restrict__ x,   const float* __restrict__ tw,
           const float* __restrict__ ta,  const float* __restrict__ tb,
           const float* __restrict__ tg,  const float* __restrict__ tmk,
           const float* __restrict__ tmv, const float* __restrict__ tmr,
           const float* __restrict__ Wk,  const float* __restrict__ bk,
           const float* __restrict__ Wv,  const float* __restrict__ bv,
           const float* __restrict__ Wr,  const float* __restrict__ br,
           const float* __restrict__ Wo,  const float* __restrict__ bo,
           ushort_t* __restrict__ Wall,   ushort_t* __restrict__ Wob,
           ushort_t* __restrict__ xk,     ushort_t* __restrict__ xv,
           ushort_t* __restrict__ xr,     ushort_t* __restrict__ kb,
           ushort_t* __restrict__ vb,     ushort_t* __restrict__ rb,
           float* __restrict__ Sloc,      float* __restrict__ Kloc,
           float* __restrict__ outp,      unsigned int* bar) {
    __shared__ alignas(16) ushort_t sh[2][2 * 128 * 64];   // 64 KiB
    const int bid = blockIdx.x;
    const int tid = threadIdx.x;

    // ---------------- phase 1: mix3 (jobs 0..8191) + weight convert (8192..9215) ----
    for (int job = bid; job < 9216; job += NBLK) {
        if (job >= 8192) {
            int bb = job - 8192;
            int m = bb >> 8;                           // 0..3
            const float* src = (m == 0) ? Wk : (m == 1) ? Wv : (m == 2) ? Wr : Wo;
            ushort_t* dst = (m == 3) ? Wob : Wall + (size_t)m * 262144;
            int i = (bb & 255) * 256 + tid;            // group of 4
            float4 v = *(const float4*)(src + (size_t)i * 4);
            union { unsigned short u[4]; uint2 p; } pk;
            pk.u[0] = f2bf(v.x); pk.u[1] = f2bf(v.y);
            pk.u[2] = f2bf(v.z); pk.u[3] = f2bf(v.w);
            *(uint2*)(dst + (size_t)i * 4) = pk.p;
            continue;
        }
        int i   = job * 256 + tid;                     // group of 4 channels
        int c4  = (i & 127) << 2;
        int row = i >> 7;                              // b*T + t
        int t   = row & (TTLEN - 1);
        float4 xc = *(const float4*)(x + (size_t)row * 512 + c4);
        float4 xp = make_float4(0.f, 0.f, 0.f, 0.f);
        if (t != 0) xp = *(const float4*)(x + (size_t)(row - 1) * 512 + c4);
        size_t o = (size_t)row * 512 + c4;
        union { unsigned short u[4]; uint2 p; } pk;
        {
            float4 tv = *(const float4*)(tmk + c4);
            pk.u[0] = f2bf(xc.x * tv.x + xp.x * (1.f - tv.x));
            pk.u[1] = f2bf(xc.y * tv.y + xp.y * (1.f - tv.y));
            pk.u[2] = f2bf(xc.z * tv.z + xp.z * (1.f - tv.z));
            pk.u[3] = f2bf(xc.w * tv.w + xp.w * (1.f - tv.w));
            *(uint2*)(xk + o) = pk.p;
        }
        {
            float4 tv = *(const float4*)(tmv + c4);
            pk.u[0] = f2bf(xc.x * tv.x + xp.x * (1.f - tv.x));
            pk.u[1] = f2bf(xc.y * tv.y + xp.y * (1.f - tv.y));
            pk.u[2] = f2bf(xc.z * tv.z + xp.z * (1.f - tv.z));
            pk.u[3] = f2bf(xc.w * tv.w + xp.w * (1.f - tv.w));
            *(uint2*)(xv + o) = pk.p;
        }
        {
            float4 tv = *(const float4*)(tmr + c4);
            pk.u[0] = f2bf(xc.x * tv.x + xp.x * (1.f - tv.x));
            pk.u[1] = f2bf(xc.y * tv.y + xp.y * (1.f - tv.y));
            pk.u[2] = f2bf(xc.z * tv.z + xp.z * (1.f - tv.z));
            pk.u[3] = f2bf(xc.w * tv.w + xp.w * (1.f - tv.w));
            *(uint2*)(xr + o) = pk.p;
        }
    }
    gbar(bar);

    const int lane = tid & 63;
    const int w    = tid >> 6;
    const int wm   = (w >> 1) << 6;
    const int wn   = (w & 1) << 6;
    const int r16  = lane & 15, q = lane >> 4;
    const int rowInW = lane >> 3, ch = lane & 7;

#define STAGE(buf, k0) {                                                        \
    const ushort_t* Ag = Abase + (k0);                                          \
    const ushort_t* Bg = Bbase + (k0);                                          \
    ushort_t* As_ = &sh[buf][0];                                                \
    ushort_t* Bs_ = &sh[buf][128 * 64];                                         \
    _Pragma("unroll")                                                           \
    for (int i = 0; i < 4; ++i) {                                               \
        int baseRow = w * 32 + i * 8;                                           \
        int row = baseRow + rowInW;                                             \
        int gch = ch ^ (row & 7);                                               \
        GLD_LDS16(Ag + (size_t)row * 512 + gch * 8, &As_[baseRow * 64]);        \
        GLD_LDS16(Bg + (size_t)row * 512 + gch * 8, &Bs_[baseRow * 64]);        \
    }                                                                           \
}
#define KLOOP() {                                                               \
    STAGE(0, 0);                                                                \
    _Pragma("unroll")                                                           \
    for (int k = 0; k < 8; ++k) {                                               \
        const int cur = k & 1;                                                  \
        if (k < 7) {                                                            \
            STAGE(cur ^ 1, (k + 1) * 64);                                       \
            asm volatile("s_waitcnt vmcnt(8)" ::: "memory");                    \
        } else {                                                                \
            asm volatile("s_waitcnt vmcnt(0)" ::: "memory");                    \
        }                                                                       \
        __builtin_amdgcn_s_barrier();                                           \
        __builtin_amdgcn_sched_barrier(0);                                      \
        {                                                                       \
            const ushort_t* As = &sh[cur][0];                                   \
            const ushort_t* Bs = &sh[cur][128 * 64];                            \
            _Pragma("unroll")                                                   \
            for (int s = 0; s < 2; ++s) {                                       \
                short8 af[4], bfr[4];                                           \
                _Pragma("unroll")                                               \
                for (int mt = 0; mt < 4; ++mt) {                                \
                    int row = wm + mt * 16 + r16;                               \
                    af[mt] = *(const short8*)(&As[row * 64 +                    \
                                (((s * 4 + q) ^ (r16 & 7)) << 3)]);             \
                }                                                               \
                _Pragma("unroll")                                               \
                for (int nt = 0; nt < 4; ++nt) {                                \
                    int row = wn + nt * 16 + r16;                               \
                    bfr[nt] = *(const short8*)(&Bs[row * 64 +                   \
                                (((s * 4 + q) ^ (r16 & 7)) << 3)]);             \
                }                                                               \
                _Pragma("unroll")                                               \
                for (int mt = 0; mt < 4; ++mt)                                  \
                    _Pragma("unroll")                                           \
                    for (int nt = 0; nt < 4; ++nt)                              \
                        acc[mt][nt] = __builtin_amdgcn_mfma_f32_16x16x32_bf16(  \
                            af[mt], bfr[nt], acc[mt][nt], 0, 0, 0);             \
            }                                                                   \
        }                                                                       \
        __builtin_amdgcn_sched_barrier(0);                                      \
        __builtin_amdgcn_s_barrier();                                           \
    }                                                                           \
}

    // ---------------- phase 2: k/v/r GEMMs (1536 jobs, 3 per block) ----------------
    for (int job = bid; job < 1536; job += NBLK) {
        __syncthreads();                      // LDS reuse guard between jobs
        const int mBlk  = (job & 127) << 7;   // M fast
        const int nTile = job >> 7;           // 0..11
        const int p     = nTile >> 2;         // band: 0=k,1=v,2=r
        const int nBlk  = (nTile & 3) << 7;   // band-local col base
        const ushort_t* A   = (p == 0) ? xk : (p == 1) ? xv : xr;
        const float* bias   = (p == 0) ? bk : (p == 1) ? bv : br;
        ushort_t* outb      = (p == 0) ? kb : (p == 1) ? vb : rb;
        const ushort_t* Abase = A + (size_t)mBlk * 512;
        const ushort_t* Bbase = Wall + (size_t)p * 262144 + (size_t)nBlk * 512;

        f32x4 acc[4][4];
#pragma unroll
        for (int a = 0; a < 4; ++a)
#pragma unroll
            for (int b = 0; b < 4; ++b) acc[a][b] = (f32x4){0.f, 0.f, 0.f, 0.f};

        KLOOP();

        // epilogue: activated bf16 subtile -> LDS repack -> dwordx4 stores
        const int nLocal0 = nBlk + wn;
        ushort_t* shf = &sh[0][0];
        const int wbase = w << 12;            // 8KB per wave
#pragma unroll
        for (int nt = 0; nt < 4; ++nt) {
            float bv_ = bias[nLocal0 + nt * 16 + r16];
#pragma unroll
            for (int mt = 0; mt < 4; ++mt) {
#pragma unroll
                for (int i = 0; i < 4; ++i) {
                    int rl = mt * 16 + (q << 2) + i;     // wave-local row 0..63
                    int cl = nt * 16 + r16;              // wave-local col 0..63
                    float v = acc[mt][nt][i] + bv_;
                    if (p == 0) v = __expf(fminf(fmaxf(v, -60.f), 30.f));
                    else if (p == 2) v = 1.f / (1.f + __expf(-v));
                    shf[wbase + rl * 64 + (cl ^ (((rl >> 2) & 3) << 4))] = f2bf(v);
                }
            }
        }
        asm volatile("s_waitcnt lgkmcnt(0)" ::: "memory");
        __builtin_amdgcn_sched_barrier(0);
#pragma unroll
        for (int i = 0; i < 8; ++i) {
            int c   = i * 64 + lane;                 // chunk id 0..511
            int rl  = c >> 3;
            int cl8 = (c & 7) << 3;
            short8 val = *(const short8*)(
                &shf[wbase + rl * 64 + (cl8 ^ (((rl >> 2) & 3) << 4))]);
            int grow = mBlk + wm + rl;
            *(short8*)(&outb[(size_t)grow * 512 + nLocal0 + cl8]) = val;
        }
    }
    gbar(bar);

    // ---------------- phase 3: scanA (512 jobs, 1 per block) ----------------
    {
        int b = bid >> 6, j = bid & 63;
        int a0 = tid * 2;
        int h = a0 >> 6;
        float r = tw[h * TTLEN + TTLEN - 2];
        int t0 = j * CLEN;
        size_t base = ((size_t)(b * TTLEN + t0)) * 512 + a0;
        const float* al = ta + h * TTLEN + t0;
        float s0 = 0.f, s1 = 0.f, sk0 = 0.f, sk1 = 0.f;
#pragma unroll 8
        for (int it = 0; it < CLEN; ++it) {
            unsigned int kk = *(const unsigned int*)(kb + base + (size_t)it * 512);
            unsigned int vv = *(const unsigned int*)(vb + base + (size_t)it * 512);
            float kf0 = bf2f(kk & 0xffff), kf1 = bf2f(kk >> 16);
            float vf0 = bf2f(vv & 0xffff), vf1 = bf2f(vv >> 16);
            float av = al[it];
            sk0 += kf0; sk1 += kf1;
            s0 = fmaf(r, s0, av * kf0 * vf0);
            s1 = fmaf(r, s1, av * kf1 * vf1);
        }
        int o = (b * NCH + j) * 512 + a0;
        Sloc[o] = s0; Sloc[o + 1] = s1;
        Kloc[o] = sk0; Kloc[o + 1] = sk1;
    }
    gbar(bar);

    // ------- phase 4: scanB, in-block chunk-prefix + replay, emit rwkv (=xk) -------
    {
        int b = bid >> 6, j = bid & 63;
        int a0 = tid * 2;
        int h = a0 >> 6;
        float r = tw[h * TTLEN + TTLEN - 2];
        float rL = r;
#pragma unroll
        for (int i = 0; i < 5; ++i) rL *= rL;       // r^32 = r^CLEN
        float s0 = 0.f, s1 = 0.f, sk0 = 0.f, sk1 = 0.f;
#pragma unroll 4
        for (int jj = 0; jj < j; ++jj) {
            int oo = (b * NCH + jj) * 512 + a0;
            float2 sl = *(const float2*)(Sloc + oo);
            float2 kl = *(const float2*)(Kloc + oo);
            s0 = fmaf(rL, s0, sl.x);
            s1 = fmaf(rL, s1, sl.y);
            sk0 += kl.x; sk1 += kl.y;
        }
        int t0 = j * CLEN;
        size_t base = ((size_t)(b * TTLEN + t0)) * 512 + a0;
        const float* al = ta + h * TTLEN + t0;
        const float* bt = tb + h * TTLEN + t0;
#pragma unroll 4
        for (int it = 0; it < CLEN; ++it) {
            unsigned int kk = *(const unsigned int*)(kb + base + (size_t)it * 512);
            unsigned int vv = *(const unsigned int*)(vb + base + (size_t)it * 512);
            unsigned int rr = *(const unsigned int*)(rb + base + (size_t)it * 512);
            float kf0 = bf2f(kk & 0xffff), kf1 = bf2f(kk >> 16);
            float vf0 = bf2f(vv & 0xffff), vf1 = bf2f(vv >> 16);
            float rf0 = bf2f(rr & 0xffff), rf1 = bf2f(rr >> 16);
            float av = al[it], btv = bt[it];
            sk0 += kf0; sk1 += kf1;
            s0 = fmaf(r, s0, av * kf0 * vf0);
            s1 = fmaf(r, s1, av * kf1 * vf1);
            float w0 = btv * s0, w1 = btv * s1;
            unsigned int outw =
                ((unsigned int)f2bf(rf1 * w1 / sk1) << 16) | f2bf(rf0 * w0 / sk0);
            *(unsigned int*)(xk + base + (size_t)it * 512) = outw;   // rwkv = xk
        }
    }
    gbar(bar);

    // ---------------- phase 5: out-projection GEMM (512 jobs, 1 per block) ----------
    {
        __syncthreads();
        const int mBlk = (bid & 127) << 7;    // M fast
        const int nBlk = (bid >> 7) << 7;     // 0..3 tiles
        const ushort_t* Abase = xk + (size_t)mBlk * 512;   // rwkv
        const ushort_t* Bbase = Wob + (size_t)nBlk * 512;

        f32x4 acc[4][4];
#pragma unroll
        for (int a = 0; a < 4; ++a)
#pragma unroll
            for (int b = 0; b < 4; ++b) acc[a][b] = (f32x4){0.f, 0.f, 0.f, 0.f};

        KLOOP();

#pragma unroll
        for (int mt = 0; mt < 4; ++mt) {
#pragma unroll
            for (int nt = 0; nt < 4; ++nt) {
                int col = nBlk + wn + nt * 16 + r16;
                float bv_ = bo[col];
#pragma unroll
                for (int i = 0; i < 4; ++i) {
                    int row = mBlk + wm + mt * 16 + (q << 2) + i;
                    float v = (acc[mt][nt][i] + bv_) * tg[row & (TTLEN - 1)];
                    outp[(size_t)row * 512 + col] = v;
                }
            }
        }
    }
#undef KLOOP
#undef STAGE
}

extern "C" void kernel_launch(void* const* d_in, const int* in_sizes, int n_in,
                              void* d_out, int out_size, void* d_ws, size_t ws_size,
                              hipStream_t stream) {
    const float* x   = (const float*)d_in[0];
    const float* tw  = (const float*)d_in[1];
    const float* ta  = (const float*)d_in[2];
    const float* tb  = (const float*)d_in[3];
    const float* tg  = (const float*)d_in[4];
    const float* tmk = (const float*)d_in[5];
    const float* tmv = (const float*)d_in[6];
    const float* tmr = (const float*)d_in[7];
    const float* Wk  = (const float*)d_in[8];
    const float* bk  = (const float*)d_in[9];
    const float* Wv  = (const float*)d_in[10];
    const float* bv  = (const float*)d_in[11];
    const float* Wr  = (const float*)d_in[12];
    const float* br  = (const float*)d_in[13];
    const float* Wo  = (const float*)d_in[14];
    const float* bo  = (const float*)d_in[15];

    char* ws = (char*)d_ws;
    ushort_t* Wall = (ushort_t*)(ws + 0);            // [1536][512] bf16 (Wk;Wv;Wr)
    ushort_t* Wob  = (ushort_t*)(ws + 1572864);      // [512][512] bf16
    ushort_t* xk   = (ushort_t*)(ws + 2097152);      // 16.78 MB each; rwkv aliases xk
    ushort_t* xv   = (ushort_t*)(ws + 18874368);
    ushort_t* xr   = (ushort_t*)(ws + 35651584);
    ushort_t* kb   = (ushort_t*)(ws + 52428800);
    ushort_t* vb   = (ushort_t*)(ws + 69206016);
    ushort_t* rb   = (ushort_t*)(ws + 85983232);
    float* Sloc = (float*)(ws + 102760448);          // 1 MB each
    float* Kloc = (float*)(ws + 103809024);
    unsigned int* bar = (unsigned int*)(ws + 104857600);   // [cnt, gen]
    float* outp = (float*)d_out;

    hipMemsetAsync(bar, 0, 64, stream);              // barrier state: stream-ordered

    rwkv_fused<<<dim3(NBLK), dim3(256), 0, stream>>>(
        x, tw, ta, tb, tg, tmk, tmv, tmr, Wk, bk, Wv, bv, Wr, br, Wo, bo,
        Wall, Wob, xk, xv, xr, kb, vb, rb, Sloc, Kloc, outp, bar);
}

// Round 10
// 200.622 us; speedup vs baseline: 3.4751x; 3.4751x over previous
//
#include <hip/hip_runtime.h>
#include <hip/hip_bf16.h>

#define TTLEN 2048
#define NCH   64
#define CLEN  32    // TTLEN / NCH

typedef unsigned short ushort_t;
typedef __attribute__((ext_vector_type(8))) short short8;
typedef __attribute__((ext_vector_type(4))) float f32x4;

__device__ __forceinline__ unsigned short f2bf(float f) {
    __hip_bfloat16 h = __float2bfloat16(f);
    return *reinterpret_cast<unsigned short*>(&h);
}
__device__ __forceinline__ float bf2f(unsigned int u16) {
    union { unsigned int i; float f; } v; v.i = u16 << 16; return v.f;
}

#define GLD_LDS16(gp, lp) __builtin_amdgcn_global_load_lds( \
    (const __attribute__((address_space(1))) void*)(gp),    \
    (__attribute__((address_space(3))) void*)(lp), 16, 0, 0)

// ---------- prep: mix3 (blocks 0..8191) + weight convert (blocks 8192..9215) ----------
__global__ void prep(const float* __restrict__ x,
                     const float* __restrict__ tmk, const float* __restrict__ tmv,
                     const float* __restrict__ tmr,
                     const float* __restrict__ Wk, const float* __restrict__ Wv,
                     const float* __restrict__ Wr, const float* __restrict__ Wo,
                     ushort_t* __restrict__ Wall, ushort_t* __restrict__ Wob,
                     ushort_t* __restrict__ xk, ushort_t* __restrict__ xv,
                     ushort_t* __restrict__ xr) {
    int bid = blockIdx.x;
    if (bid >= 8192) {
        int bb = bid - 8192;
        int m = bb >> 8;                           // 0..3
        const float* src = (m == 0) ? Wk : (m == 1) ? Wv : (m == 2) ? Wr : Wo;
        ushort_t* dst = (m == 3) ? Wob : Wall + (size_t)m * 262144;
        int i = (bb & 255) * 256 + threadIdx.x;    // group of 4
        float4 v = *(const float4*)(src + (size_t)i * 4);
        union { unsigned short u[4]; uint2 p; } pk;
        pk.u[0] = f2bf(v.x); pk.u[1] = f2bf(v.y); pk.u[2] = f2bf(v.z); pk.u[3] = f2bf(v.w);
        *(uint2*)(dst + (size_t)i * 4) = pk.p;
        return;
    }
    int i   = bid * 256 + threadIdx.x;             // group of 4 channels
    int c4  = (i & 127) << 2;
    int row = i >> 7;                              // b*T + t
    int t   = row & (TTLEN - 1);
    float4 xc = *(const float4*)(x + (size_t)row * 512 + c4);
    float4 xp = make_float4(0.f, 0.f, 0.f, 0.f);
    if (t != 0) xp = *(const float4*)(x + (size_t)(row - 1) * 512 + c4);
    size_t o = (size_t)row * 512 + c4;
    union { unsigned short u[4]; uint2 p; } pk;
    {
        float4 tv = *(const float4*)(tmk + c4);
        pk.u[0] = f2bf(xc.x * tv.x + xp.x * (1.f - tv.x));
        pk.u[1] = f2bf(xc.y * tv.y + xp.y * (1.f - tv.y));
        pk.u[2] = f2bf(xc.z * tv.z + xp.z * (1.f - tv.z));
        pk.u[3] = f2bf(xc.w * tv.w + xp.w * (1.f - tv.w));
        *(uint2*)(xk + o) = pk.p;
    }
    {
        float4 tv = *(const float4*)(tmv + c4);
        pk.u[0] = f2bf(xc.x * tv.x + xp.x * (1.f - tv.x));
        pk.u[1] = f2bf(xc.y * tv.y + xp.y * (1.f - tv.y));
        pk.u[2] = f2bf(xc.z * tv.z + xp.z * (1.f - tv.z));
        pk.u[3] = f2bf(xc.w * tv.w + xp.w * (1.f - tv.w));
        *(uint2*)(xv + o) = pk.p;
    }
    {
        float4 tv = *(const float4*)(tmr + c4);
        pk.u[0] = f2bf(xc.x * tv.x + xp.x * (1.f - tv.x));
        pk.u[1] = f2bf(xc.y * tv.y + xp.y * (1.f - tv.y));
        pk.u[2] = f2bf(xc.z * tv.z + xp.z * (1.f - tv.z));
        pk.u[3] = f2bf(xc.w * tv.w + xp.w * (1.f - tv.w));
        *(uint2*)(xr + o) = pk.p;
    }
}

// ------- m97-style GEMM + 2-buffer LDS pipeline (r6-verified: 47.3us, MfmaUtil 20%) -------
// Per K-step: stage(k+1 -> other buf); vmcnt(8); s_barrier; compute(cur); s_barrier.
// No vmcnt(0) drain until the final step. M-fast grid (verified FETCH 103->31MB).
// MODE 0: fused k/v/r (N=1536, bf16 out + activation, LDS-repack dwordx4 stores)
// MODE 1: out-projection (N=512, fp32 out * gamma[t])
template <int MODE>
__launch_bounds__(256)
__global__ void gemm_m97(const ushort_t* __restrict__ Axk, const ushort_t* __restrict__ Axv,
                         const ushort_t* __restrict__ Axr, const ushort_t* __restrict__ W,
                         const float* __restrict__ b0, const float* __restrict__ b1,
                         const float* __restrict__ b2,
                         ushort_t* __restrict__ o0, ushort_t* __restrict__ o1,
                         ushort_t* __restrict__ o2,
                         float* __restrict__ fout, const float* __restrict__ gamma) {
    __shared__ alignas(16) ushort_t sh[2][2 * 128 * 64];   // [buf][As|Bs] = 64 KiB
    const int tid  = threadIdx.x;
    const int lane = tid & 63;
    const int w    = tid >> 6;
    const int wm   = (w >> 1) << 6;
    const int wn   = (w & 1) << 6;
    const int mBlk = blockIdx.x << 7;   // M fast
    const int nBlk = blockIdx.y << 7;
    const int r16  = lane & 15, q = lane >> 4;
    const int rowInW = lane >> 3, ch = lane & 7;

    const int p = nBlk >> 9;   // projection band (MODE 0)
    const ushort_t* A = (MODE == 1) ? Axk : (p == 0 ? Axk : (p == 1 ? Axv : Axr));
    const ushort_t* Abase = A + (size_t)mBlk * 512;
    const ushort_t* Bbase = W + (size_t)nBlk * 512;

    f32x4 acc[4][4];
#pragma unroll
    for (int a = 0; a < 4; ++a)
#pragma unroll
        for (int b = 0; b < 4; ++b) acc[a][b] = (f32x4){0.f, 0.f, 0.f, 0.f};

#define STAGE(buf, k0) {                                                        \
    const ushort_t* Ag = Abase + (k0);                                          \
    const ushort_t* Bg = Bbase + (k0);                                          \
    ushort_t* As_ = &sh[buf][0];                                                \
    ushort_t* Bs_ = &sh[buf][128 * 64];                                         \
    _Pragma("unroll")                                                           \
    for (int i = 0; i < 4; ++i) {                                               \
        int baseRow = w * 32 + i * 8;                                           \
        int row = baseRow + rowInW;                                             \
        int gch = ch ^ (row & 7);                                               \
        GLD_LDS16(Ag + (size_t)row * 512 + gch * 8, &As_[baseRow * 64]);        \
        GLD_LDS16(Bg + (size_t)row * 512 + gch * 8, &Bs_[baseRow * 64]);        \
    }                                                                           \
}

    STAGE(0, 0);                         // prologue: tile 0 in flight
#pragma unroll
    for (int k = 0; k < 8; ++k) {
        const int cur = k & 1;
        if (k < 7) {
            STAGE(cur ^ 1, (k + 1) * 64);                      // prefetch next tile
            asm volatile("s_waitcnt vmcnt(8)" ::: "memory");   // cur's 8 landed
        } else {
            asm volatile("s_waitcnt vmcnt(0)" ::: "memory");   // pipeline tail
        }
        __builtin_amdgcn_s_barrier();
        __builtin_amdgcn_sched_barrier(0);   // pin ds_reads after the barrier
        {
            const ushort_t* As = &sh[cur][0];
            const ushort_t* Bs = &sh[cur][128 * 64];
#pragma unroll
            for (int s = 0; s < 2; ++s) {
                short8 af[4], bfr[4];
#pragma unroll
                for (int mt = 0; mt < 4; ++mt) {
                    int row = wm + mt * 16 + r16;
                    af[mt] = *(const short8*)(&As[row * 64 + (((s * 4 + q) ^ (r16 & 7)) << 3)]);
                }
#pragma unroll
                for (int nt = 0; nt < 4; ++nt) {
                    int row = wn + nt * 16 + r16;
                    bfr[nt] = *(const short8*)(&Bs[row * 64 + (((s * 4 + q) ^ (r16 & 7)) << 3)]);
                }
#pragma unroll
                for (int mt = 0; mt < 4; ++mt)
#pragma unroll
                    for (int nt = 0; nt < 4; ++nt)
                        acc[mt][nt] = __builtin_amdgcn_mfma_f32_16x16x32_bf16(
                            af[mt], bfr[nt], acc[mt][nt], 0, 0, 0);
            }
        }
        __builtin_amdgcn_sched_barrier(0);   // keep reads/MFMA before the barrier
        __builtin_amdgcn_s_barrier();        // cur fully consumed -> re-stageable
    }
#undef STAGE
    // after final barrier + vmcnt(0): LDS free for epilogue reuse

    if (MODE == 0) {
        const float* bias = (p == 0) ? b0 : (p == 1) ? b1 : b2;
        ushort_t* outp = (p == 0) ? o0 : (p == 1) ? o1 : o2;
        const int nLocal0 = (nBlk & 511) + wn;     // wave's first col (band-local)
        ushort_t* shf = &sh[0][0];
        const int wbase = w << 12;                  // 8KB per wave
        // ---- activated bf16 subtile -> LDS (q-XOR swizzle, 2-way max banking) ----
#pragma unroll
        for (int nt = 0; nt < 4; ++nt) {
            float bv = bias[nLocal0 + nt * 16 + r16];
#pragma unroll
            for (int mt = 0; mt < 4; ++mt) {
#pragma unroll
                for (int i = 0; i < 4; ++i) {
                    int rl = mt * 16 + (q << 2) + i;     // wave-local row 0..63
                    int cl = nt * 16 + r16;              // wave-local col 0..63
                    float v = acc[mt][nt][i] + bv;
                    if (p == 0) v = __expf(fminf(fmaxf(v, -60.f), 30.f));
                    else if (p == 2) v = 1.f / (1.f + __expf(-v));
                    shf[wbase + rl * 64 + (cl ^ (((rl >> 2) & 3) << 4))] = f2bf(v);
                }
            }
        }
        asm volatile("s_waitcnt lgkmcnt(0)" ::: "memory");
        __builtin_amdgcn_sched_barrier(0);
        // ---- read back contiguous 16B chunks, store dwordx4 ----
#pragma unroll
        for (int i = 0; i < 8; ++i) {
            int c   = i * 64 + lane;                 // chunk id 0..511
            int rl  = c >> 3;
            int cl8 = (c & 7) << 3;
            short8 val = *(const short8*)(
                &shf[wbase + rl * 64 + (cl8 ^ (((rl >> 2) & 3) << 4))]);
            int grow = mBlk + wm + rl;
            *(short8*)(&outp[(size_t)grow * 512 + nLocal0 + cl8]) = val;
        }
    } else {
#pragma unroll
        for (int mt = 0; mt < 4; ++mt) {
#pragma unroll
            for (int nt = 0; nt < 4; ++nt) {
                int col = nBlk + wn + nt * 16 + r16;
                float bv = b0[col];
#pragma unroll
                for (int i = 0; i < 4; ++i) {
                    int row = mBlk + wm + mt * 16 + (q << 2) + i;
                    float v = (acc[mt][nt][i] + bv) * gamma[row & (TTLEN - 1)];
                    fout[(size_t)row * 512 + col] = v;
                }
            }
        }
    }
}

// ---------------- scan phase A (r5-verified): per-chunk local (S, sum_k) ----------------
__global__ void scanA(const ushort_t* __restrict__ kb, const ushort_t* __restrict__ vb,
                      const float* __restrict__ tw, const float* __restrict__ alpha,
                      float* __restrict__ Sloc, float* __restrict__ Kloc) {
    int tid = threadIdx.x;
    int b = blockIdx.x >> 6, j = blockIdx.x & 63;
    int a0 = tid * 2;
    int h = a0 >> 6;
    float r = tw[h * TTLEN + TTLEN - 2];
    int t0 = j * CLEN;
    size_t base = ((size_t)(b * TTLEN + t0)) * 512 + a0;
    const float* al = alpha + h * TTLEN + t0;
    float s0 = 0.f, s1 = 0.f, sk0 = 0.f, sk1 = 0.f;
#pragma unroll 8
    for (int it = 0; it < CLEN; ++it) {
        unsigned int kk = *(const unsigned int*)(kb + base + (size_t)it * 512);
        unsigned int vv = *(const unsigned int*)(vb + base + (size_t)it * 512);
        float kf0 = bf2f(kk & 0xffff), kf1 = bf2f(kk >> 16);
        float vf0 = bf2f(vv & 0xffff), vf1 = bf2f(vv >> 16);
        float av = al[it];
        sk0 += kf0; sk1 += kf1;
        s0 = fmaf(r, s0, av * kf0 * vf0);
        s1 = fmaf(r, s1, av * kf1 * vf1);
    }
    int o = (b * NCH + j) * 512 + a0;
    Sloc[o] = s0; Sloc[o + 1] = s1;
    Kloc[o] = sk0; Kloc[o + 1] = sk1;
}

// ------- scan phase B (r5-verified): in-block chunk-prefix + replay, emit rwkv -------
// Prefix Horner order identical to the old scanMid -> bit-identical numerics.
__global__ void scanB(const ushort_t* __restrict__ kb, const ushort_t* __restrict__ vb,
                      const ushort_t* __restrict__ rb,
                      const float* __restrict__ tw, const float* __restrict__ alpha,
                      const float* __restrict__ beta,
                      const float* __restrict__ Sloc, const float* __restrict__ Kloc,
                      ushort_t* __restrict__ rwkv) {
    int tid = threadIdx.x;
    int b = blockIdx.x >> 6, j = blockIdx.x & 63;
    int a0 = tid * 2;
    int h = a0 >> 6;
    float r = tw[h * TTLEN + TTLEN - 2];
    float rL = r;
#pragma unroll
    for (int i = 0; i < 5; ++i) rL *= rL;       // r^32 = r^CLEN
    float s0 = 0.f, s1 = 0.f, sk0 = 0.f, sk1 = 0.f;
#pragma unroll 4
    for (int jj = 0; jj < j; ++jj) {
        int oo = (b * NCH + jj) * 512 + a0;
        float2 sl = *(const float2*)(Sloc + oo);
        float2 kl = *(const float2*)(Kloc + oo);
        s0 = fmaf(rL, s0, sl.x);
        s1 = fmaf(rL, s1, sl.y);
        sk0 += kl.x; sk1 += kl.y;
    }
    int t0 = j * CLEN;
    size_t base = ((size_t)(b * TTLEN + t0)) * 512 + a0;
    const float* al = alpha + h * TTLEN + t0;
    const float* bt = beta + h * TTLEN + t0;
#pragma unroll 4
    for (int it = 0; it < CLEN; ++it) {
        unsigned int kk = *(const unsigned int*)(kb + base + (size_t)it * 512);
        unsigned int vv = *(const unsigned int*)(vb + base + (size_t)it * 512);
        unsigned int rr = *(const unsigned int*)(rb + base + (size_t)it * 512);
        float kf0 = bf2f(kk & 0xffff), kf1 = bf2f(kk >> 16);
        float vf0 = bf2f(vv & 0xffff), vf1 = bf2f(vv >> 16);
        float rf0 = bf2f(rr & 0xffff), rf1 = bf2f(rr >> 16);
        float av = al[it], btv = bt[it];
        sk0 += kf0; sk1 += kf1;
        s0 = fmaf(r, s0, av * kf0 * vf0);
        s1 = fmaf(r, s1, av * kf1 * vf1);
        float w0 = btv * s0, w1 = btv * s1;
        unsigned int outw = ((unsigned int)f2bf(rf1 * w1 / sk1) << 16) | f2bf(rf0 * w0 / sk0);
        *(unsigned int*)(rwkv + base + (size_t)it * 512) = outw;
    }
}

extern "C" void kernel_launch(void* const* d_in, const int* in_sizes, int n_in,
                              void* d_out, int out_size, void* d_ws, size_t ws_size,
                              hipStream_t stream) {
    const float* x   = (const float*)d_in[0];
    const float* tw  = (const float*)d_in[1];
    const float* ta  = (const float*)d_in[2];
    const float* tb  = (const float*)d_in[3];
    const float* tg  = (const float*)d_in[4];
    const float* tmk = (const float*)d_in[5];
    const float* tmv = (const float*)d_in[6];
    const float* tmr = (const float*)d_in[7];
    const float* Wk  = (const float*)d_in[8];
    const float* bk  = (const float*)d_in[9];
    const float* Wv  = (const float*)d_in[10];
    const float* bv  = (const float*)d_in[11];
    const float* Wr  = (const float*)d_in[12];
    const float* br  = (const float*)d_in[13];
    const float* Wo  = (const float*)d_in[14];
    const float* bo  = (const float*)d_in[15];

    char* ws = (char*)d_ws;
    ushort_t* Wall = (ushort_t*)(ws + 0);            // [1536][512] bf16 (Wk;Wv;Wr)
    ushort_t* Wob  = (ushort_t*)(ws + 1572864);      // [512][512] bf16
    ushort_t* xk   = (ushort_t*)(ws + 2097152);      // 16.78 MB each
    ushort_t* xv   = (ushort_t*)(ws + 18874368);
    ushort_t* xr   = (ushort_t*)(ws + 35651584);
    ushort_t* kb   = (ushort_t*)(ws + 52428800);
    ushort_t* vb   = (ushort_t*)(ws + 69206016);
    ushort_t* rb   = (ushort_t*)(ws + 85983232);
    ushort_t* rwkv = xk;                             // xk dead after gemm<0>
    float* Sloc = (float*)(ws + 102760448);          // 1 MB each
    float* Kloc = (float*)(ws + 103809024);

    prep<<<9216, 256, 0, stream>>>(x, tmk, tmv, tmr, Wk, Wv, Wr, Wo,
                                   Wall, Wob, xk, xv, xr);

    gemm_m97<0><<<dim3(128, 12), 256, 0, stream>>>(xk, xv, xr, Wall, bk, bv, br,
                                                   kb, vb, rb, nullptr, nullptr);

    scanA<<<512, 256, 0, stream>>>(kb, vb, tw, ta, Sloc, Kloc);
    scanB<<<512, 256, 0, stream>>>(kb, vb, rb, tw, ta, tb, Sloc, Kloc, rwkv);

    gemm_m97<1><<<dim3(128, 4), 256, 0, stream>>>(rwkv, nullptr, nullptr, Wob, bo, nullptr,
                                                  nullptr, nullptr, nullptr, nullptr,
                                                  (float*)d_out, tg);
}

// Round 11
// 199.334 us; speedup vs baseline: 3.4976x; 1.0065x over previous
//
#include <hip/hip_runtime.h>
#include <hip/hip_bf16.h>

#define TTLEN 2048
#define NCH   64
#define CLEN  32    // TTLEN / NCH

typedef unsigned short ushort_t;
typedef __attribute__((ext_vector_type(8))) short short8;
typedef __attribute__((ext_vector_type(4))) float f32x4;

__device__ __forceinline__ unsigned short f2bf(float f) {
    __hip_bfloat16 h = __float2bfloat16(f);
    return *reinterpret_cast<unsigned short*>(&h);
}
__device__ __forceinline__ float bf2f(unsigned int u16) {
    union { unsigned int i; float f; } v; v.i = u16 << 16; return v.f;
}

#define GLD_LDS16(gp, lp) __builtin_amdgcn_global_load_lds( \
    (const __attribute__((address_space(1))) void*)(gp),    \
    (__attribute__((address_space(3))) void*)(lp), 16, 0, 0)

// ---------- prep: mix3 (blocks 0..8191) + weight convert (blocks 8192..9215) ----------
__global__ void prep(const float* __restrict__ x,
                     const float* __restrict__ tmk, const float* __restrict__ tmv,
                     const float* __restrict__ tmr,
                     const float* __restrict__ Wk, const float* __restrict__ Wv,
                     const float* __restrict__ Wr, const float* __restrict__ Wo,
                     ushort_t* __restrict__ Wall, ushort_t* __restrict__ Wob,
                     ushort_t* __restrict__ xk, ushort_t* __restrict__ xv,
                     ushort_t* __restrict__ xr) {
    int bid = blockIdx.x;
    if (bid >= 8192) {
        int bb = bid - 8192;
        int m = bb >> 8;                           // 0..3
        const float* src = (m == 0) ? Wk : (m == 1) ? Wv : (m == 2) ? Wr : Wo;
        ushort_t* dst = (m == 3) ? Wob : Wall + (size_t)m * 262144;
        int i = (bb & 255) * 256 + threadIdx.x;    // group of 4
        float4 v = *(const float4*)(src + (size_t)i * 4);
        union { unsigned short u[4]; uint2 p; } pk;
        pk.u[0] = f2bf(v.x); pk.u[1] = f2bf(v.y); pk.u[2] = f2bf(v.z); pk.u[3] = f2bf(v.w);
        *(uint2*)(dst + (size_t)i * 4) = pk.p;
        return;
    }
    int i   = bid * 256 + threadIdx.x;             // group of 4 channels
    int c4  = (i & 127) << 2;
    int row = i >> 7;                              // b*T + t
    int t   = row & (TTLEN - 1);
    float4 xc = *(const float4*)(x + (size_t)row * 512 + c4);
    float4 xp = make_float4(0.f, 0.f, 0.f, 0.f);
    if (t != 0) xp = *(const float4*)(x + (size_t)(row - 1) * 512 + c4);
    size_t o = (size_t)row * 512 + c4;
    union { unsigned short u[4]; uint2 p; } pk;
    {
        float4 tv = *(const float4*)(tmk + c4);
        pk.u[0] = f2bf(xc.x * tv.x + xp.x * (1.f - tv.x));
        pk.u[1] = f2bf(xc.y * tv.y + xp.y * (1.f - tv.y));
        pk.u[2] = f2bf(xc.z * tv.z + xp.z * (1.f - tv.z));
        pk.u[3] = f2bf(xc.w * tv.w + xp.w * (1.f - tv.w));
        *(uint2*)(xk + o) = pk.p;
    }
    {
        float4 tv = *(const float4*)(tmv + c4);
        pk.u[0] = f2bf(xc.x * tv.x + xp.x * (1.f - tv.x));
        pk.u[1] = f2bf(xc.y * tv.y + xp.y * (1.f - tv.y));
        pk.u[2] = f2bf(xc.z * tv.z + xp.z * (1.f - tv.z));
        pk.u[3] = f2bf(xc.w * tv.w + xp.w * (1.f - tv.w));
        *(uint2*)(xv + o) = pk.p;
    }
    {
        float4 tv = *(const float4*)(tmr + c4);
        pk.u[0] = f2bf(xc.x * tv.x + xp.x * (1.f - tv.x));
        pk.u[1] = f2bf(xc.y * tv.y + xp.y * (1.f - tv.y));
        pk.u[2] = f2bf(xc.z * tv.z + xp.z * (1.f - tv.z));
        pk.u[3] = f2bf(xc.w * tv.w + xp.w * (1.f - tv.w));
        *(uint2*)(xr + o) = pk.p;
    }
}

// ---- m97 GEMM, BK=32, 3-buffer LDS, 2-step-deep prefetch (counted vmcnt) ----
// Step k: stage(k+2 -> buf (k+2)%3); vmcnt(8) [stages k+1,k+2 in flight, k landed];
// s_barrier; 16 MFMA on buf k%3; s_barrier. Tail: vmcnt(4) @k=14, vmcnt(0) @k=15.
// 48 KiB LDS -> 3 blocks/CU (was 2). Swizzle chunk ^= (row&3)^((row>>2)&3): 2-way
// max bank aliasing on fragment ds_reads (free). K-order identical to BK=64 version
// -> bit-identical numerics. M-fast grid (verified FETCH 103->31MB).
// MODE 0: fused k/v/r (N=1536, bf16 out + activation, LDS-repack dwordx4 stores)
// MODE 1: out-projection (N=512, fp32 out * gamma[t])
template <int MODE>
__launch_bounds__(256)
__global__ void gemm_m97(const ushort_t* __restrict__ Axk, const ushort_t* __restrict__ Axv,
                         const ushort_t* __restrict__ Axr, const ushort_t* __restrict__ W,
                         const float* __restrict__ b0, const float* __restrict__ b1,
                         const float* __restrict__ b2,
                         ushort_t* __restrict__ o0, ushort_t* __restrict__ o1,
                         ushort_t* __restrict__ o2,
                         float* __restrict__ fout, const float* __restrict__ gamma) {
    __shared__ alignas(16) ushort_t sh[3][2 * 128 * 32];   // 3 x (As|Bs) = 48 KiB
    const int tid  = threadIdx.x;
    const int lane = tid & 63;
    const int w    = tid >> 6;
    const int wm   = (w >> 1) << 6;
    const int wn   = (w & 1) << 6;
    const int mBlk = blockIdx.x << 7;   // M fast
    const int nBlk = blockIdx.y << 7;
    const int r16  = lane & 15, q = lane >> 4;
    const int rowInW = lane >> 2, ch = lane & 3;   // 4 chunks of 16B per 64B row

    const int p = nBlk >> 9;   // projection band (MODE 0)
    const ushort_t* A = (MODE == 1) ? Axk : (p == 0 ? Axk : (p == 1 ? Axv : Axr));
    const ushort_t* Abase = A + (size_t)mBlk * 512;
    const ushort_t* Bbase = W + (size_t)nBlk * 512;

    f32x4 acc[4][4];
#pragma unroll
    for (int a = 0; a < 4; ++a)
#pragma unroll
        for (int b = 0; b < 4; ++b) acc[a][b] = (f32x4){0.f, 0.f, 0.f, 0.f};

#define SWZ(row) (((row) & 3) ^ (((row) >> 2) & 3))
#define STAGE(buf, k0) {                                                        \
    const ushort_t* Ag = Abase + (k0);                                          \
    const ushort_t* Bg = Bbase + (k0);                                          \
    ushort_t* As_ = &sh[buf][0];                                                \
    ushort_t* Bs_ = &sh[buf][128 * 32];                                         \
    _Pragma("unroll")                                                           \
    for (int i = 0; i < 2; ++i) {                                               \
        int rowBase = i * 64 + w * 16;           /* wave-uniform LDS base */    \
        int row = rowBase + rowInW;                                             \
        int gch = ch ^ SWZ(row);                 /* pre-swizzled source */      \
        GLD_LDS16(Ag + (size_t)row * 512 + gch * 8, &As_[rowBase * 32]);        \
        GLD_LDS16(Bg + (size_t)row * 512 + gch * 8, &Bs_[rowBase * 32]);        \
    }                                                                           \
}

    STAGE(0, 0); STAGE(1, 32);           // prologue: 2 tiles in flight
#pragma unroll
    for (int k = 0; k < 16; ++k) {
        const int cur = k % 3;
        if (k + 2 < 16) {
            STAGE((k + 2) % 3, (k + 2) * 32);                  // prefetch 2 ahead
            asm volatile("s_waitcnt vmcnt(8)" ::: "memory");   // tile k landed
        } else if (k == 14) {
            asm volatile("s_waitcnt vmcnt(4)" ::: "memory");
        } else {
            asm volatile("s_waitcnt vmcnt(0)" ::: "memory");   // pipeline tail
        }
        __builtin_amdgcn_s_barrier();
        __builtin_amdgcn_sched_barrier(0);   // pin ds_reads after the barrier
        {
            const ushort_t* As = &sh[cur][0];
            const ushort_t* Bs = &sh[cur][128 * 32];
            short8 af[4], bfr[4];
#pragma unroll
            for (int mt = 0; mt < 4; ++mt) {
                int row = wm + mt * 16 + r16;
                af[mt] = *(const short8*)(&As[row * 32 + ((q ^ SWZ(row)) << 3)]);
            }
#pragma unroll
            for (int nt = 0; nt < 4; ++nt) {
                int row = wn + nt * 16 + r16;
                bfr[nt] = *(const short8*)(&Bs[row * 32 + ((q ^ SWZ(row)) << 3)]);
            }
#pragma unroll
            for (int mt = 0; mt < 4; ++mt)
#pragma unroll
                for (int nt = 0; nt < 4; ++nt)
                    acc[mt][nt] = __builtin_amdgcn_mfma_f32_16x16x32_bf16(
                        af[mt], bfr[nt], acc[mt][nt], 0, 0, 0);
        }
        __builtin_amdgcn_sched_barrier(0);   // keep reads/MFMA before the barrier
        __builtin_amdgcn_s_barrier();        // cur fully consumed -> re-stageable
    }
#undef STAGE
#undef SWZ
    // after final barrier + vmcnt(0): LDS free for epilogue reuse

    if (MODE == 0) {
        const float* bias = (p == 0) ? b0 : (p == 1) ? b1 : b2;
        ushort_t* outp = (p == 0) ? o0 : (p == 1) ? o1 : o2;
        const int nLocal0 = (nBlk & 511) + wn;     // wave's first col (band-local)
        ushort_t* shf = &sh[0][0];
        const int wbase = w << 12;                  // 8KB per wave (32KB of 48KB)
        // ---- activated bf16 subtile -> LDS (q-XOR swizzle, 2-way max banking) ----
#pragma unroll
        for (int nt = 0; nt < 4; ++nt) {
            float bv = bias[nLocal0 + nt * 16 + r16];
#pragma unroll
            for (int mt = 0; mt < 4; ++mt) {
#pragma unroll
                for (int i = 0; i < 4; ++i) {
                    int rl = mt * 16 + (q << 2) + i;     // wave-local row 0..63
                    int cl = nt * 16 + r16;              // wave-local col 0..63
                    float v = acc[mt][nt][i] + bv;
                    if (p == 0) v = __expf(fminf(fmaxf(v, -60.f), 30.f));
                    else if (p == 2) v = 1.f / (1.f + __expf(-v));
                    shf[wbase + rl * 64 + (cl ^ (((rl >> 2) & 3) << 4))] = f2bf(v);
                }
            }
        }
        asm volatile("s_waitcnt lgkmcnt(0)" ::: "memory");
        __builtin_amdgcn_sched_barrier(0);
        // ---- read back contiguous 16B chunks, store dwordx4 ----
#pragma unroll
        for (int i = 0; i < 8; ++i) {
            int c   = i * 64 + lane;                 // chunk id 0..511
            int rl  = c >> 3;
            int cl8 = (c & 7) << 3;
            short8 val = *(const short8*)(
                &shf[wbase + rl * 64 + (cl8 ^ (((rl >> 2) & 3) << 4))]);
            int grow = mBlk + wm + rl;
            *(short8*)(&outp[(size_t)grow * 512 + nLocal0 + cl8]) = val;
        }
    } else {
#pragma unroll
        for (int mt = 0; mt < 4; ++mt) {
#pragma unroll
            for (int nt = 0; nt < 4; ++nt) {
                int col = nBlk + wn + nt * 16 + r16;
                float bv = b0[col];
#pragma unroll
                for (int i = 0; i < 4; ++i) {
                    int row = mBlk + wm + mt * 16 + (q << 2) + i;
                    float v = (acc[mt][nt][i] + bv) * gamma[row & (TTLEN - 1)];
                    fout[(size_t)row * 512 + col] = v;
                }
            }
        }
    }
}

// ---------------- scan phase A (r5-verified): per-chunk local (S, sum_k) ----------------
__global__ void scanA(const ushort_t* __restrict__ kb, const ushort_t* __restrict__ vb,
                      const float* __restrict__ tw, const float* __restrict__ alpha,
                      float* __restrict__ Sloc, float* __restrict__ Kloc) {
    int tid = threadIdx.x;
    int b = blockIdx.x >> 6, j = blockIdx.x & 63;
    int a0 = tid * 2;
    int h = a0 >> 6;
    float r = tw[h * TTLEN + TTLEN - 2];
    int t0 = j * CLEN;
    size_t base = ((size_t)(b * TTLEN + t0)) * 512 + a0;
    const float* al = alpha + h * TTLEN + t0;
    float s0 = 0.f, s1 = 0.f, sk0 = 0.f, sk1 = 0.f;
#pragma unroll 8
    for (int it = 0; it < CLEN; ++it) {
        unsigned int kk = *(const unsigned int*)(kb + base + (size_t)it * 512);
        unsigned int vv = *(const unsigned int*)(vb + base + (size_t)it * 512);
        float kf0 = bf2f(kk & 0xffff), kf1 = bf2f(kk >> 16);
        float vf0 = bf2f(vv & 0xffff), vf1 = bf2f(vv >> 16);
        float av = al[it];
        sk0 += kf0; sk1 += kf1;
        s0 = fmaf(r, s0, av * kf0 * vf0);
        s1 = fmaf(r, s1, av * kf1 * vf1);
    }
    int o = (b * NCH + j) * 512 + a0;
    Sloc[o] = s0; Sloc[o + 1] = s1;
    Kloc[o] = sk0; Kloc[o + 1] = sk1;
}

// ------- scan phase B (r5-verified): in-block chunk-prefix + replay, emit rwkv -------
// Prefix Horner order identical to the old scanMid -> bit-identical numerics.
__global__ void scanB(const ushort_t* __restrict__ kb, const ushort_t* __restrict__ vb,
                      const ushort_t* __restrict__ rb,
                      const float* __restrict__ tw, const float* __restrict__ alpha,
                      const float* __restrict__ beta,
                      const float* __restrict__ Sloc, const float* __restrict__ Kloc,
                      ushort_t* __restrict__ rwkv) {
    int tid = threadIdx.x;
    int b = blockIdx.x >> 6, j = blockIdx.x & 63;
    int a0 = tid * 2;
    int h = a0 >> 6;
    float r = tw[h * TTLEN + TTLEN - 2];
    float rL = r;
#pragma unroll
    for (int i = 0; i < 5; ++i) rL *= rL;       // r^32 = r^CLEN
    float s0 = 0.f, s1 = 0.f, sk0 = 0.f, sk1 = 0.f;
#pragma unroll 4
    for (int jj = 0; jj < j; ++jj) {
        int oo = (b * NCH + jj) * 512 + a0;
        float2 sl = *(const float2*)(Sloc + oo);
        float2 kl = *(const float2*)(Kloc + oo);
        s0 = fmaf(rL, s0, sl.x);
        s1 = fmaf(rL, s1, sl.y);
        sk0 += kl.x; sk1 += kl.y;
    }
    int t0 = j * CLEN;
    size_t base = ((size_t)(b * TTLEN + t0)) * 512 + a0;
    const float* al = alpha + h * TTLEN + t0;
    const float* bt = beta + h * TTLEN + t0;
#pragma unroll 4
    for (int it = 0; it < CLEN; ++it) {
        unsigned int kk = *(const unsigned int*)(kb + base + (size_t)it * 512);
        unsigned int vv = *(const unsigned int*)(vb + base + (size_t)it * 512);
        unsigned int rr = *(const unsigned int*)(rb + base + (size_t)it * 512);
        float kf0 = bf2f(kk & 0xffff), kf1 = bf2f(kk >> 16);
        float vf0 = bf2f(vv & 0xffff), vf1 = bf2f(vv >> 16);
        float rf0 = bf2f(rr & 0xffff), rf1 = bf2f(rr >> 16);
        float av = al[it], btv = bt[it];
        sk0 += kf0; sk1 += kf1;
        s0 = fmaf(r, s0, av * kf0 * vf0);
        s1 = fmaf(r, s1, av * kf1 * vf1);
        float w0 = btv * s0, w1 = btv * s1;
        unsigned int outw = ((unsigned int)f2bf(rf1 * w1 / sk1) << 16) | f2bf(rf0 * w0 / sk0);
        *(unsigned int*)(rwkv + base + (size_t)it * 512) = outw;
    }
}

extern "C" void kernel_launch(void* const* d_in, const int* in_sizes, int n_in,
                              void* d_out, int out_size, void* d_ws, size_t ws_size,
                              hipStream_t stream) {
    const float* x   = (const float*)d_in[0];
    const float* tw  = (const float*)d_in[1];
    const float* ta  = (const float*)d_in[2];
    const float* tb  = (const float*)d_in[3];
    const float* tg  = (const float*)d_in[4];
    const float* tmk = (const float*)d_in[5];
    const float* tmv = (const float*)d_in[6];
    const float* tmr = (const float*)d_in[7];
    const float* Wk  = (const float*)d_in[8];
    const float* bk  = (const float*)d_in[9];
    const float* Wv  = (const float*)d_in[10];
    const float* bv  = (const float*)d_in[11];
    const float* Wr  = (const float*)d_in[12];
    const float* br  = (const float*)d_in[13];
    const float* Wo  = (const float*)d_in[14];
    const float* bo  = (const float*)d_in[15];

    char* ws = (char*)d_ws;
    ushort_t* Wall = (ushort_t*)(ws + 0);            // [1536][512] bf16 (Wk;Wv;Wr)
    ushort_t* Wob  = (ushort_t*)(ws + 1572864);      // [512][512] bf16
    ushort_t* xk   = (ushort_t*)(ws + 2097152);      // 16.78 MB each
    ushort_t* xv   = (ushort_t*)(ws + 18874368);
    ushort_t* xr   = (ushort_t*)(ws + 35651584);
    ushort_t* kb   = (ushort_t*)(ws + 52428800);
    ushort_t* vb   = (ushort_t*)(ws + 69206016);
    ushort_t* rb   = (ushort_t*)(ws + 85983232);
    ushort_t* rwkv = xk;                             // xk dead after gemm<0>
    float* Sloc = (float*)(ws + 102760448);          // 1 MB each
    float* Kloc = (float*)(ws + 103809024);

    prep<<<9216, 256, 0, stream>>>(x, tmk, tmv, tmr, Wk, Wv, Wr, Wo,
                                   Wall, Wob, xk, xv, xr);

    gemm_m97<0><<<dim3(128, 12), 256, 0, stream>>>(xk, xv, xr, Wall, bk, bv, br,
                                                   kb, vb, rb, nullptr, nullptr);

    scanA<<<512, 256, 0, stream>>>(kb, vb, tw, ta, Sloc, Kloc);
    scanB<<<512, 256, 0, stream>>>(kb, vb, rb, tw, ta, tb, Sloc, Kloc, rwkv);

    gemm_m97<1><<<dim3(128, 4), 256, 0, stream>>>(rwkv, nullptr, nullptr, Wob, bo, nullptr,
                                                  nullptr, nullptr, nullptr, nullptr,
                                                  (float*)d_out, tg);
}